// Round 1
// baseline (241.813 us; speedup 1.0000x reference)
//
#include <hip/hip_runtime.h>

// DPQ embedding, MI355X. N=131072 tokens, EMB=128, D=8 subspaces x SUB=16, K=128 codes.
// Pipeline:
//  k1_stats:  gather x rows, accumulate per-block moment stats (G, Sx, h, Sn, S2)
//  k2_reduce: deterministic tree-reduce of block partials
//  k3_final:  stats + centroids -> alpha[k], beta[d][k]  (BN folded into affine score)
//  k4_main:   per (token,d): dot over 128 codes from LDS (broadcast), argmax, write centroid

constexpr int NTOK = 131072;   // 1024*128
constexpr int ST   = 2320;     // stats stride (2312 used, padded)
constexpr float EPS = 0.001f;

// stats layout: G: d*256 + s*16 + s'  (2048)
//               Sx: 2048 + d*16 + s   (128)
//               h : 2176 + d*16 + s   (128)
//               S2: 2304 + d          (8)    -> 2312 total

__global__ __launch_bounds__(256) void k1_stats(const int* __restrict__ ids,
                                                const float* __restrict__ wemb,
                                                float* __restrict__ partials,
                                                int tpb)
{
    __shared__ float xs[32][132];   // 32 tokens x 128 floats, padded to 132
    __shared__ float nrm[32][8];
    const int t = threadIdx.x;
    const int b = blockIdx.x;

    float g[4][4];
#pragma unroll
    for (int i = 0; i < 4; ++i)
#pragma unroll
        for (int j = 0; j < 4; ++j) g[i][j] = 0.f;
    float sx = 0.f, hh = 0.f, s2 = 0.f;

    const int d_g = t >> 4;                 // t<128: Gram task (d, 4x4 tile)
    const int r0  = ((t >> 2) & 3) << 2;
    const int c0  = (t & 3) << 2;
    const int u   = t & 127;                // t>=128: (d,s) task
    const int d_s = u >> 4;
    const int s_s = u & 15;

    const int nchunks = tpb >> 5;
    for (int ch = 0; ch < nchunks; ++ch) {
        const int n0 = b * tpb + ch * 32;
        // ---- load 32 token rows (coalesced: 32 lanes x float4 = one 512B row) ----
#pragma unroll
        for (int rep = 0; rep < 4; ++rep) {
            int i = t + rep * 256;
            int n = i >> 5, f = i & 31;
            int id = ids[n0 + n];
            float4 v = *(const float4*)(wemb + (size_t)id * 128 + f * 4);
            *(float4*)(&xs[n][f * 4]) = v;
        }
        __syncthreads();
        // ---- per-(n,d) norms: 256 threads = 32x8 ----
        {
            int n = t >> 3, dd = t & 7;
            const float* xp = &xs[n][dd * 16];
            float4 a = *(const float4*)(xp);
            float4 bq = *(const float4*)(xp + 4);
            float4 c = *(const float4*)(xp + 8);
            float4 dq = *(const float4*)(xp + 12);
            float acc = a.x*a.x + a.y*a.y + a.z*a.z + a.w*a.w;
            acc += bq.x*bq.x + bq.y*bq.y + bq.z*bq.z + bq.w*bq.w;
            acc += c.x*c.x + c.y*c.y + c.z*c.z + c.w*c.w;
            acc += dq.x*dq.x + dq.y*dq.y + dq.z*dq.z + dq.w*dq.w;
            nrm[n][dd] = acc;
        }
        __syncthreads();
        // ---- accumulate stats over the chunk ----
        if (t < 128) {
            for (int n = 0; n < 32; ++n) {
                const float* xp = &xs[n][d_g * 16];
                float4 av = *(const float4*)(xp + r0);
                float4 bv = *(const float4*)(xp + c0);
                float aa[4] = {av.x, av.y, av.z, av.w};
                float bb[4] = {bv.x, bv.y, bv.z, bv.w};
#pragma unroll
                for (int i = 0; i < 4; ++i)
#pragma unroll
                    for (int j = 0; j < 4; ++j)
                        g[i][j] = fmaf(aa[i], bb[j], g[i][j]);
            }
        } else {
            for (int n = 0; n < 32; ++n) {
                float xv = xs[n][d_s * 16 + s_s];
                float nv = nrm[n][d_s];
                sx += xv;
                hh = fmaf(nv, xv, hh);
                if (s_s == 0) s2 = fmaf(nv, nv, s2);
            }
        }
        __syncthreads();
    }
    float* pb = partials + (size_t)b * ST;
    if (t < 128) {
        const int base = d_g * 256;
#pragma unroll
        for (int i = 0; i < 4; ++i)
#pragma unroll
            for (int j = 0; j < 4; ++j)
                pb[base + (r0 + i) * 16 + (c0 + j)] = g[i][j];
    } else {
        pb[2048 + d_s * 16 + s_s] = sx;
        pb[2176 + d_s * 16 + s_s] = hh;
        if (s_s == 0) pb[2304 + d_s] = s2;
    }
}

__global__ __launch_bounds__(256) void k2_reduce(const float* __restrict__ partials,
                                                 float* __restrict__ stats, int nblocks)
{
    int idx = blockIdx.x * 256 + threadIdx.x;
    if (idx >= 2312) return;
    float s = 0.f;
    for (int b = 0; b < nblocks; ++b) s += partials[(size_t)b * ST + idx];
    stats[idx] = s;
}

__global__ __launch_bounds__(128) void k3_final(const float* __restrict__ stats,
                                                const float* __restrict__ centroids,
                                                float2* __restrict__ ab)
{
    __shared__ float st[2312];
    const int t = threadIdx.x;
    for (int i = t; i < 2312; i += 128) st[i] = stats[i];
    __syncthreads();
    const int k = t;   // 128 threads, one per code

    double Sn[8], Sn_tot = 0.0, S2_tot = 0.0;
#pragma unroll
    for (int d = 0; d < 8; ++d) {
        double s = 0.0;
        for (int ss = 0; ss < 16; ++ss) s += (double)st[d * 256 + ss * 17];
        Sn[d] = s; Sn_tot += s;
        S2_tot += (double)st[2304 + d];
    }
    double sr = -Sn_tot, sr2 = S2_tot;
    double ncd[8];
    for (int d = 0; d < 8; ++d) {
        const float* cp = centroids + d * 2048 + k * 16;
        float cv[16];
#pragma unroll
        for (int s = 0; s < 16; ++s) cv[s] = cp[s];
        double nc = 0, cdSx = 0, ch = 0, cGc = 0;
        for (int s = 0; s < 16; ++s) {
            nc   += (double)cv[s] * cv[s];
            cdSx += (double)cv[s] * st[2048 + d * 16 + s];
            ch   += (double)cv[s] * st[2176 + d * 16 + s];
            double rd = 0;
            for (int s2i = 0; s2i < 16; ++s2i)
                rd += (double)st[d * 256 + s * 16 + s2i] * cv[s2i];
            cGc += (double)cv[s] * rd;
        }
        ncd[d] = nc;
        sr  += 2.0 * cdSx - (double)NTOK * nc;
        sr2 += 4.0 * cGc + (double)NTOK * nc * nc + 2.0 * nc * Sn[d]
               - 4.0 * ch - 4.0 * nc * cdSx;
    }
    const double M = (double)NTOK * 8.0;
    double mean = sr / M;
    double var  = sr2 / M - mean * mean;
    float alpha = (float)(1.0 / sqrt(var + (double)EPS));
#pragma unroll
    for (int d = 0; d < 8; ++d) {
        float beta = (float)((double)alpha * (-ncd[d] - mean));
        ab[d * 128 + k] = make_float2(2.f * alpha, beta);
    }
}

__global__ __launch_bounds__(256) void k4_main(const int* __restrict__ ids,
                                               const float* __restrict__ wemb,
                                               const float* __restrict__ centroids,
                                               const float2* __restrict__ ab,
                                               float* __restrict__ out)
{
    __shared__ float cs[128][16];
    __shared__ float2 gb_s[128];
    const int t = threadIdx.x;
    const int d = blockIdx.y;
    const float* cd = centroids + d * 2048;
#pragma unroll
    for (int i = 0; i < 2; ++i)
        ((float4*)cs)[t + i * 256] = ((const float4*)cd)[t + i * 256];
    if (t < 128) gb_s[t] = ab[d * 128 + t];
    __syncthreads();

    const int n0 = blockIdx.x * 1024 + t;   // 4 tokens per thread, stride 256
    float x[4][16];
    float nx2[4], best[4];
    int code[4];
#pragma unroll
    for (int j = 0; j < 4; ++j) {
        const int n = n0 + j * 256;
        const float* xp = wemb + (size_t)ids[n] * 128 + d * 16;
        float4 v0 = *(const float4*)(xp);
        float4 v1 = *(const float4*)(xp + 4);
        float4 v2 = *(const float4*)(xp + 8);
        float4 v3 = *(const float4*)(xp + 12);
        x[j][0] = v0.x; x[j][1] = v0.y; x[j][2]  = v0.z; x[j][3]  = v0.w;
        x[j][4] = v1.x; x[j][5] = v1.y; x[j][6]  = v1.z; x[j][7]  = v1.w;
        x[j][8] = v2.x; x[j][9] = v2.y; x[j][10] = v2.z; x[j][11] = v2.w;
        x[j][12] = v3.x; x[j][13] = v3.y; x[j][14] = v3.z; x[j][15] = v3.w;
        float s = 0.f;
#pragma unroll
        for (int q = 0; q < 16; ++q) s = fmaf(x[j][q], x[j][q], s);
        nx2[j] = -0.5f * s;            // score = 2a*(dot - nx/2) + beta
        best[j] = -3.4e38f;
        code[j] = 0;
    }
#pragma unroll 2
    for (int k = 0; k < 128; ++k) {
        float2 gb = gb_s[k];
        float4 c0 = *(const float4*)(&cs[k][0]);
        float4 c1 = *(const float4*)(&cs[k][4]);
        float4 c2 = *(const float4*)(&cs[k][8]);
        float4 c3 = *(const float4*)(&cs[k][12]);
        float c[16] = {c0.x, c0.y, c0.z, c0.w, c1.x, c1.y, c1.z, c1.w,
                       c2.x, c2.y, c2.z, c2.w, c3.x, c3.y, c3.z, c3.w};
#pragma unroll
        for (int j = 0; j < 4; ++j) {
            float acc = nx2[j];
#pragma unroll
            for (int s = 0; s < 16; ++s) acc = fmaf(c[s], x[j][s], acc);
            float score = fmaf(gb.x, acc, gb.y);
            bool p = score > best[j];           // strict > keeps FIRST max (argmax tie rule)
            best[j] = p ? score : best[j];
            code[j] = p ? k : code[j];
        }
    }
#pragma unroll
    for (int j = 0; j < 4; ++j) {
        const int n = n0 + j * 256;
        const float* cw = cd + code[j] * 16;    // L1/L2-resident, 64KB hot set
        float* op = out + (size_t)n * 128 + d * 16;
#pragma unroll
        for (int s = 0; s < 16; s += 4) {
            float4 cv = *(const float4*)(cw + s);
            float4 o;
            // match reference: out = x + (c - x) in fp32
            o.x = x[j][s + 0] + (cv.x - x[j][s + 0]);
            o.y = x[j][s + 1] + (cv.y - x[j][s + 1]);
            o.z = x[j][s + 2] + (cv.z - x[j][s + 2]);
            o.w = x[j][s + 3] + (cv.w - x[j][s + 3]);
            *(float4*)(op + s) = o;
        }
    }
}

extern "C" void kernel_launch(void* const* d_in, const int* in_sizes, int n_in,
                              void* d_out, int out_size, void* d_ws, size_t ws_size,
                              hipStream_t stream)
{
    const int* ids    = (const int*)d_in[0];
    const float* wemb = (const float*)d_in[1];
    const float* cent = (const float*)d_in[2];
    float* out = (float*)d_out;
    float* ws  = (float*)d_ws;

    // choose pass-1 block count by available workspace
    int p1b = 512;
    if (ws_size < ((size_t)512 * ST + 2320 + 2048) * 4) p1b = 256;
    if (ws_size < ((size_t)256 * ST + 2320 + 2048) * 4) p1b = 128;
    const int tpb = NTOK / p1b;

    float* partials = ws;
    float* stats    = ws + (size_t)p1b * ST;
    float2* ab      = (float2*)(stats + 2320);

    hipLaunchKernelGGL(k1_stats,  dim3(p1b),     dim3(256), 0, stream, ids, wemb, partials, tpb);
    hipLaunchKernelGGL(k2_reduce, dim3(10),      dim3(256), 0, stream, partials, stats, p1b);
    hipLaunchKernelGGL(k3_final,  dim3(1),       dim3(128), 0, stream, stats, cent, ab);
    hipLaunchKernelGGL(k4_main,   dim3(128, 8),  dim3(256), 0, stream, ids, wemb, cent, ab, out);
}

// Round 2
// 126.268 us; speedup vs baseline: 1.9151x; 1.9151x over previous
//
#include <hip/hip_runtime.h>

// DPQ embedding, MI355X. N=131072 tokens, EMB=128, D=8 subspaces x SUB=16, K=128 codes.
// Pipeline:
//  k1_stats:  gather x rows, accumulate per-block moment stats (G, Sx, h, Sn, S2)
//  k2a/k2b:   deterministic two-stage tree-reduce of block partials (in-place)
//  k3_final:  stats + centroids -> alpha[k], beta[d][k]  (BN folded into affine score)
//  k4_main:   per (token,d): dot over 128 codes from LDS (broadcast), argmax, write centroid

constexpr int NTOK = 131072;   // 1024*128
constexpr int ST   = 2320;     // stats stride (2312 used, padded)
constexpr float EPS = 0.001f;

// stats layout: G: d*256 + s*16 + s'  (2048)
//               Sx: 2048 + d*16 + s   (128)
//               h : 2176 + d*16 + s   (128)
//               S2: 2304 + d          (8)    -> 2312 total

__global__ __launch_bounds__(256) void k1_stats(const int* __restrict__ ids,
                                                const float* __restrict__ wemb,
                                                float* __restrict__ partials,
                                                int tpb)
{
    __shared__ float xs[32][132];   // 32 tokens x 128 floats, padded to 132
    __shared__ float nrm[32][8];
    const int t = threadIdx.x;
    const int b = blockIdx.x;

    float g[4][4];
#pragma unroll
    for (int i = 0; i < 4; ++i)
#pragma unroll
        for (int j = 0; j < 4; ++j) g[i][j] = 0.f;
    float sx = 0.f, hh = 0.f, s2 = 0.f;

    const int d_g = t >> 4;                 // t<128: Gram task (d, 4x4 tile)
    const int r0  = ((t >> 2) & 3) << 2;
    const int c0  = (t & 3) << 2;
    const int u   = t & 127;                // t>=128: (d,s) task
    const int d_s = u >> 4;
    const int s_s = u & 15;

    const int nchunks = tpb >> 5;
    for (int ch = 0; ch < nchunks; ++ch) {
        const int n0 = b * tpb + ch * 32;
        // ---- load 32 token rows (coalesced: 32 lanes x float4 = one 512B row) ----
#pragma unroll
        for (int rep = 0; rep < 4; ++rep) {
            int i = t + rep * 256;
            int n = i >> 5, f = i & 31;
            int id = ids[n0 + n];
            float4 v = *(const float4*)(wemb + (size_t)id * 128 + f * 4);
            *(float4*)(&xs[n][f * 4]) = v;
        }
        __syncthreads();
        // ---- per-(n,d) norms: 256 threads = 32x8 ----
        {
            int n = t >> 3, dd = t & 7;
            const float* xp = &xs[n][dd * 16];
            float4 a = *(const float4*)(xp);
            float4 bq = *(const float4*)(xp + 4);
            float4 c = *(const float4*)(xp + 8);
            float4 dq = *(const float4*)(xp + 12);
            float acc = a.x*a.x + a.y*a.y + a.z*a.z + a.w*a.w;
            acc += bq.x*bq.x + bq.y*bq.y + bq.z*bq.z + bq.w*bq.w;
            acc += c.x*c.x + c.y*c.y + c.z*c.z + c.w*c.w;
            acc += dq.x*dq.x + dq.y*dq.y + dq.z*dq.z + dq.w*dq.w;
            nrm[n][dd] = acc;
        }
        __syncthreads();
        // ---- accumulate stats over the chunk ----
        if (t < 128) {
            for (int n = 0; n < 32; ++n) {
                const float* xp = &xs[n][d_g * 16];
                float4 av = *(const float4*)(xp + r0);
                float4 bv = *(const float4*)(xp + c0);
                float aa[4] = {av.x, av.y, av.z, av.w};
                float bb[4] = {bv.x, bv.y, bv.z, bv.w};
#pragma unroll
                for (int i = 0; i < 4; ++i)
#pragma unroll
                    for (int j = 0; j < 4; ++j)
                        g[i][j] = fmaf(aa[i], bb[j], g[i][j]);
            }
        } else {
            for (int n = 0; n < 32; ++n) {
                float xv = xs[n][d_s * 16 + s_s];
                float nv = nrm[n][d_s];
                sx += xv;
                hh = fmaf(nv, xv, hh);
                if (s_s == 0) s2 = fmaf(nv, nv, s2);
            }
        }
        __syncthreads();
    }
    float* pb = partials + (size_t)b * ST;
    if (t < 128) {
        const int base = d_g * 256;
#pragma unroll
        for (int i = 0; i < 4; ++i)
#pragma unroll
            for (int j = 0; j < 4; ++j)
                pb[base + (r0 + i) * 16 + (c0 + j)] = g[i][j];
    } else {
        pb[2048 + d_s * 16 + s_s] = sx;
        pb[2176 + d_s * 16 + s_s] = hh;
        if (s_s == 0) pb[2304 + d_s] = s2;
    }
}

// ---- stage A: fold nb blocks down to 32, in place. grid (10, 32). ----
// thread (y, idx) sums b = y, y+32, y+64, ... < nb into partials[y*ST+idx].
// 8 independent accumulators keep 8 loads in flight (the old single-stage
// version serialized 512 loads at HBM latency -> 122us).
__global__ __launch_bounds__(256) void k2a_reduce(float* __restrict__ partials, int nb)
{
    const int idx = blockIdx.x * 256 + threadIdx.x;
    if (idx >= 2312) return;
    const int y = blockIdx.y;          // 0..31
    float acc[8] = {0.f, 0.f, 0.f, 0.f, 0.f, 0.f, 0.f, 0.f};
    int b = y;
    while (b + 7 * 32 < nb) {
#pragma unroll
        for (int u = 0; u < 8; ++u)
            acc[u] += partials[(size_t)(b + u * 32) * ST + idx];
        b += 8 * 32;
    }
    while (b < nb) { acc[0] += partials[(size_t)b * ST + idx]; b += 32; }
    float s = ((acc[0] + acc[1]) + (acc[2] + acc[3]))
            + ((acc[4] + acc[5]) + (acc[6] + acc[7]));
    partials[(size_t)y * ST + idx] = s;
}

// ---- stage B: sum the 32 survivors (L2-resident, fully unrolled). grid 10. ----
__global__ __launch_bounds__(256) void k2b_reduce(const float* __restrict__ partials,
                                                  float* __restrict__ stats)
{
    const int idx = blockIdx.x * 256 + threadIdx.x;
    if (idx >= 2312) return;
    float acc[8] = {0.f, 0.f, 0.f, 0.f, 0.f, 0.f, 0.f, 0.f};
#pragma unroll
    for (int j = 0; j < 4; ++j)
#pragma unroll
        for (int u = 0; u < 8; ++u)
            acc[u] += partials[(size_t)(j * 8 + u) * ST + idx];
    stats[idx] = ((acc[0] + acc[1]) + (acc[2] + acc[3]))
               + ((acc[4] + acc[5]) + (acc[6] + acc[7]));
}

__global__ __launch_bounds__(128) void k3_final(const float* __restrict__ stats,
                                                const float* __restrict__ centroids,
                                                float2* __restrict__ ab)
{
    __shared__ float st[2312];
    const int t = threadIdx.x;
    for (int i = t; i < 2312; i += 128) st[i] = stats[i];
    __syncthreads();
    const int k = t;   // 128 threads, one per code

    double Sn[8], Sn_tot = 0.0, S2_tot = 0.0;
#pragma unroll
    for (int d = 0; d < 8; ++d) {
        double s = 0.0;
        for (int ss = 0; ss < 16; ++ss) s += (double)st[d * 256 + ss * 17];
        Sn[d] = s; Sn_tot += s;
        S2_tot += (double)st[2304 + d];
    }
    double sr = -Sn_tot, sr2 = S2_tot;
    double ncd[8];
    for (int d = 0; d < 8; ++d) {
        const float* cp = centroids + d * 2048 + k * 16;
        float cv[16];
#pragma unroll
        for (int s = 0; s < 16; ++s) cv[s] = cp[s];
        double nc = 0, cdSx = 0, ch = 0, cGc = 0;
        for (int s = 0; s < 16; ++s) {
            nc   += (double)cv[s] * cv[s];
            cdSx += (double)cv[s] * st[2048 + d * 16 + s];
            ch   += (double)cv[s] * st[2176 + d * 16 + s];
            double rd = 0;
            for (int s2i = 0; s2i < 16; ++s2i)
                rd += (double)st[d * 256 + s * 16 + s2i] * cv[s2i];
            cGc += (double)cv[s] * rd;
        }
        ncd[d] = nc;
        sr  += 2.0 * cdSx - (double)NTOK * nc;
        sr2 += 4.0 * cGc + (double)NTOK * nc * nc + 2.0 * nc * Sn[d]
               - 4.0 * ch - 4.0 * nc * cdSx;
    }
    const double M = (double)NTOK * 8.0;
    double mean = sr / M;
    double var  = sr2 / M - mean * mean;
    float alpha = (float)(1.0 / sqrt(var + (double)EPS));
#pragma unroll
    for (int d = 0; d < 8; ++d) {
        float beta = (float)((double)alpha * (-ncd[d] - mean));
        ab[d * 128 + k] = make_float2(2.f * alpha, beta);
    }
}

__global__ __launch_bounds__(256) void k4_main(const int* __restrict__ ids,
                                               const float* __restrict__ wemb,
                                               const float* __restrict__ centroids,
                                               const float2* __restrict__ ab,
                                               float* __restrict__ out)
{
    __shared__ float cs[128][16];
    __shared__ float2 gb_s[128];
    const int t = threadIdx.x;
    const int d = blockIdx.y;
    const float* cd = centroids + d * 2048;
#pragma unroll
    for (int i = 0; i < 2; ++i)
        ((float4*)cs)[t + i * 256] = ((const float4*)cd)[t + i * 256];
    if (t < 128) gb_s[t] = ab[d * 128 + t];
    __syncthreads();

    const int n0 = blockIdx.x * 1024 + t;   // 4 tokens per thread, stride 256
    float x[4][16];
    float nx2[4], best[4];
    int code[4];
#pragma unroll
    for (int j = 0; j < 4; ++j) {
        const int n = n0 + j * 256;
        const float* xp = wemb + (size_t)ids[n] * 128 + d * 16;
        float4 v0 = *(const float4*)(xp);
        float4 v1 = *(const float4*)(xp + 4);
        float4 v2 = *(const float4*)(xp + 8);
        float4 v3 = *(const float4*)(xp + 12);
        x[j][0] = v0.x; x[j][1] = v0.y; x[j][2]  = v0.z; x[j][3]  = v0.w;
        x[j][4] = v1.x; x[j][5] = v1.y; x[j][6]  = v1.z; x[j][7]  = v1.w;
        x[j][8] = v2.x; x[j][9] = v2.y; x[j][10] = v2.z; x[j][11] = v2.w;
        x[j][12] = v3.x; x[j][13] = v3.y; x[j][14] = v3.z; x[j][15] = v3.w;
        float s = 0.f;
#pragma unroll
        for (int q = 0; q < 16; ++q) s = fmaf(x[j][q], x[j][q], s);
        nx2[j] = -0.5f * s;            // score = 2a*(dot - nx/2) + beta
        best[j] = -3.4e38f;
        code[j] = 0;
    }
#pragma unroll 2
    for (int k = 0; k < 128; ++k) {
        float2 gb = gb_s[k];
        float4 c0 = *(const float4*)(&cs[k][0]);
        float4 c1 = *(const float4*)(&cs[k][4]);
        float4 c2 = *(const float4*)(&cs[k][8]);
        float4 c3 = *(const float4*)(&cs[k][12]);
        float c[16] = {c0.x, c0.y, c0.z, c0.w, c1.x, c1.y, c1.z, c1.w,
                       c2.x, c2.y, c2.z, c2.w, c3.x, c3.y, c3.z, c3.w};
#pragma unroll
        for (int j = 0; j < 4; ++j) {
            float acc = nx2[j];
#pragma unroll
            for (int s = 0; s < 16; ++s) acc = fmaf(c[s], x[j][s], acc);
            float score = fmaf(gb.x, acc, gb.y);
            bool p = score > best[j];           // strict > keeps FIRST max (argmax tie rule)
            best[j] = p ? score : best[j];
            code[j] = p ? k : code[j];
        }
    }
#pragma unroll
    for (int j = 0; j < 4; ++j) {
        const int n = n0 + j * 256;
        const float* cw = cd + code[j] * 16;    // L1/L2-resident, 64KB hot set
        float* op = out + (size_t)n * 128 + d * 16;
#pragma unroll
        for (int s = 0; s < 16; s += 4) {
            float4 cv = *(const float4*)(cw + s);
            float4 o;
            // match reference: out = x + (c - x) in fp32
            o.x = x[j][s + 0] + (cv.x - x[j][s + 0]);
            o.y = x[j][s + 1] + (cv.y - x[j][s + 1]);
            o.z = x[j][s + 2] + (cv.z - x[j][s + 2]);
            o.w = x[j][s + 3] + (cv.w - x[j][s + 3]);
            *(float4*)(op + s) = o;
        }
    }
}

extern "C" void kernel_launch(void* const* d_in, const int* in_sizes, int n_in,
                              void* d_out, int out_size, void* d_ws, size_t ws_size,
                              hipStream_t stream)
{
    const int* ids    = (const int*)d_in[0];
    const float* wemb = (const float*)d_in[1];
    const float* cent = (const float*)d_in[2];
    float* out = (float*)d_out;
    float* ws  = (float*)d_ws;

    // choose pass-1 block count by available workspace
    int p1b = 512;
    if (ws_size < ((size_t)512 * ST + 2320 + 2048) * 4) p1b = 256;
    if (ws_size < ((size_t)256 * ST + 2320 + 2048) * 4) p1b = 128;
    const int tpb = NTOK / p1b;

    float* partials = ws;
    float* stats    = ws + (size_t)p1b * ST;
    float2* ab      = (float2*)(stats + 2320);

    hipLaunchKernelGGL(k1_stats,   dim3(p1b),     dim3(256), 0, stream, ids, wemb, partials, tpb);
    hipLaunchKernelGGL(k2a_reduce, dim3(10, 32),  dim3(256), 0, stream, partials, p1b);
    hipLaunchKernelGGL(k2b_reduce, dim3(10),      dim3(256), 0, stream, partials, stats);
    hipLaunchKernelGGL(k3_final,   dim3(1),       dim3(128), 0, stream, stats, cent, ab);
    hipLaunchKernelGGL(k4_main,    dim3(128, 8),  dim3(256), 0, stream, ids, wemb, cent, ab, out);
}